// Round 4
// baseline (53485.596 us; speedup 1.0000x reference)
//
#include <hip/hip_runtime.h>
#include <hip/hip_cooperative_groups.h>

namespace cg = cooperative_groups;

typedef short s16x8 __attribute__((ext_vector_type(8)));
typedef unsigned short us8 __attribute__((ext_vector_type(8)));
typedef float f32x4 __attribute__((ext_vector_type(4)));

#define NWG_SCAN 64
#define TC 16   // time-chunk length

// ---------- helpers ----------
__device__ __forceinline__ ushort f2bf(float f) {
  union { float f; unsigned u; } v; v.f = f;
  unsigned u = v.u;
  u += 0x7fffu + ((u >> 16) & 1u);
  return (ushort)(u >> 16);
}
__device__ __forceinline__ float bf2f(ushort h) {
  union { unsigned u; float f; } v; v.u = ((unsigned)h) << 16; return v.f;
}
__device__ __forceinline__ float sigm(float x) { return 1.f / (1.f + __expf(-x)); }
__device__ __forceinline__ float tanh_(float x) { return 1.f - 2.f / (__expf(2.f * x) + 1.f); }

#define MFMA __builtin_amdgcn_mfma_f32_16x16x32_bf16

// ---------- transpose + split-convert: dst_{hi,lo}[n][k] = split(src[k][n]) ----------
__global__ void tr_cvt_split(const float* __restrict__ src, ushort* __restrict__ hi,
                             ushort* __restrict__ lo, int kbits, int Nsrc, int total) {
  int K1 = (1 << kbits) - 1;
  for (int i = blockIdx.x * blockDim.x + threadIdx.x; i < total; i += gridDim.x * blockDim.x) {
    int n = i >> kbits, k = i & K1;
    float v = src[(size_t)k * Nsrc + n];
    ushort h = f2bf(v);
    hi[i] = h;
    lo[i] = f2bf(v - bf2f(h));
  }
}

// ---------- 3-term split GEMM: C[M,N] f32 = A[M,K] f32 * (Bh+Bl)[N,K]^T ----------
// A is split hi/lo in staging; product = Ah*Bh + Al*Bh + Ah*Bl  (ll term dropped).
// A_SC: chunk-row ar maps to global row (ar>>4)*512 + t0 + (ar&15)  (TC=16).
// C_MODE 0: f32, contiguous chunk rows, no bias. C_MODE 1: f32 + bias, scattered rows.
template <int A_SC, int C_MODE>
__global__ __launch_bounds__(256) void gemm3(
    const float* __restrict__ A, const ushort* __restrict__ Bh, const ushort* __restrict__ Bl,
    float* __restrict__ Cout, const float* __restrict__ bias,
    int M, int N, int K, int t0) {
  __shared__ __align__(16) ushort Ahs[128][72];
  __shared__ __align__(16) ushort Als[128][72];
  __shared__ __align__(16) ushort Bhs[128][72];
  __shared__ __align__(16) ushort Bls[128][72];
  const int bm = blockIdx.x, bn = blockIdx.y;
  const int tid = threadIdx.x, lane = tid & 63;
  const int w = tid >> 6;
  const int wm = (w >> 1) * 64, wn = (w & 1) * 64;
  const int lr = lane & 15;
  const int lk = (lane >> 4) * 8;
  f32x4 acc[4][4] = {};
  for (int k0 = 0; k0 < K; k0 += 64) {
#pragma unroll
    for (int i = 0; i < 4; ++i) {
      int chunk = tid + i * 256;
      int row = chunk >> 3, c = (chunk & 7) * 8;
      int ar = bm * 128 + row;
      size_t grow = A_SC ? ((size_t)(ar >> 4) * 512 + t0 + (ar & 15)) : (size_t)ar;
      const float* srcp = A + grow * K + k0 + c;
      float4 v0 = *(const float4*)(srcp);
      float4 v1 = *(const float4*)(srcp + 4);
      float vv0 = v0.x, vv1 = v0.y, vv2 = v0.z, vv3 = v0.w;
      float vv4 = v1.x, vv5 = v1.y, vv6 = v1.z, vv7 = v1.w;
      us8 uh, ul;
#define SPLIT_E(e, val) { ushort h_ = f2bf(val); uh[e] = h_; ul[e] = f2bf((val) - bf2f(h_)); }
      SPLIT_E(0, vv0) SPLIT_E(1, vv1) SPLIT_E(2, vv2) SPLIT_E(3, vv3)
      SPLIT_E(4, vv4) SPLIT_E(5, vv5) SPLIT_E(6, vv6) SPLIT_E(7, vv7)
#undef SPLIT_E
      *(us8*)(&Ahs[row][c]) = uh;
      *(us8*)(&Als[row][c]) = ul;
      *(int4*)(&Bhs[row][c]) = *(const int4*)(&Bh[(size_t)(bn * 128 + row) * K + k0 + c]);
      *(int4*)(&Bls[row][c]) = *(const int4*)(&Bl[(size_t)(bn * 128 + row) * K + k0 + c]);
    }
    __syncthreads();
#pragma unroll
    for (int kk = 0; kk < 64; kk += 32) {
      s16x8 ah[4], al[4], bh[4], bl[4];
#pragma unroll
      for (int i = 0; i < 4; ++i) {
        ah[i] = *(const s16x8*)(&Ahs[wm + i * 16 + lr][kk + lk]);
        al[i] = *(const s16x8*)(&Als[wm + i * 16 + lr][kk + lk]);
      }
#pragma unroll
      for (int j = 0; j < 4; ++j) {
        bh[j] = *(const s16x8*)(&Bhs[wn + j * 16 + lr][kk + lk]);
        bl[j] = *(const s16x8*)(&Bls[wn + j * 16 + lr][kk + lk]);
      }
#pragma unroll
      for (int i = 0; i < 4; ++i)
#pragma unroll
        for (int j = 0; j < 4; ++j) {
          acc[i][j] = MFMA(ah[i], bh[j], acc[i][j], 0, 0, 0);
          acc[i][j] = MFMA(al[i], bh[j], acc[i][j], 0, 0, 0);
          acc[i][j] = MFMA(ah[i], bl[j], acc[i][j], 0, 0, 0);
        }
    }
    __syncthreads();
  }
#pragma unroll
  for (int i = 0; i < 4; ++i)
#pragma unroll
    for (int j = 0; j < 4; ++j)
#pragma unroll
      for (int r = 0; r < 4; ++r) {
        int lrow = bm * 128 + wm + i * 16 + (lane >> 4) * 4 + r;
        int gcol = bn * 128 + wn + j * 16 + lr;
        float v = acc[i][j][r];
        if (C_MODE == 1) {
          size_t grow = (size_t)(lrow >> 4) * 512 + t0 + (lrow & 15);
          Cout[grow * N + gcol] = v + bias[gcol];
        } else {
          Cout[(size_t)lrow * N + gcol] = v;
        }
      }
}

// ---------- persistent GRU scan: one chunk of TC steps for one layer ----------
// Cooperative launch; 64 WGs x 256 thr. WG wgc owns output cols [wgc*16, +16).
// Full f32-grade precision: P f32; weights hi/lo (hi + Wg_lo in LDS, Wz/Wr lo from L2);
// h and r*h as bf16 hi/lo pairs; h carry in f32.
struct ScanArgs {
  const float* P;             // [64*TC][3072] f32 chunk (z|r|g)
  const float *bz, *br, *bg;
  const ushort *WhzrH, *WhzrL; // [2048][1024] bf16 hi/lo
  const ushort *WhgH, *WhgL;   // [1024][1024] bf16 hi/lo
  const float* h0;
  int layer, t0;
  float* h32g;                // [64][1024] f32 carry
  ushort *hbh, *hbl;          // [64][1024] bf16 hi/lo of h
  ushort *rhh, *rhl;          // [64][1024] bf16 hi/lo of r*h
  float* Sout;                // [64*TC][1024] f32 chunk
  float* hidout;              // [64][2][1024] f32
};

__global__ __launch_bounds__(256) void gru_scan(ScanArgs A) {
  cg::grid_group grid = cg::this_grid();
  __shared__ __align__(16) ushort Wz[16][1032];
  __shared__ __align__(16) ushort Wr[16][1032];
  __shared__ __align__(16) ushort Wg[16][1032];
  __shared__ __align__(16) ushort Wgl[16][1032];
  const int tid = threadIdx.x, lane = tid & 63;
  const int rb = tid >> 6;                    // rowblock 0..3
  const int wgc = blockIdx.x;                 // col slice 0..63
  const int lr = lane & 15, lkq = lane >> 4;
  const int cz = wgc * 16 + lr;               // this lane's output column

  // stage weight hi-slices (+ Wg lo) into LDS
  {
    const ushort* srcz = A.WhzrH + (size_t)(wgc * 16) * 1024;
    const ushort* srcr = A.WhzrH + (size_t)(1024 + wgc * 16) * 1024;
    const ushort* srcg = A.WhgH + (size_t)(wgc * 16) * 1024;
    const ushort* srcgl = A.WhgL + (size_t)(wgc * 16) * 1024;
#pragma unroll
    for (int j = 0; j < 8; ++j) {
      int id = tid + j * 256;
      int row = id >> 7, ko = (id & 127) * 8;
      *(int4*)(&Wz[row][ko]) = *(const int4*)(srcz + row * 1024 + ko);
      *(int4*)(&Wr[row][ko]) = *(const int4*)(srcr + row * 1024 + ko);
      *(int4*)(&Wg[row][ko]) = *(const int4*)(srcg + row * 1024 + ko);
      *(int4*)(&Wgl[row][ko]) = *(const int4*)(srcgl + row * 1024 + ko);
    }
  }

  const int b0 = rb * 16 + lkq * 4;
  float h32[4], zv[4];
  const float bzc = A.bz[cz], brc = A.br[cz], bgc = A.bg[cz];

  if (A.t0 == 0) {
#pragma unroll
    for (int r = 0; r < 4; ++r) {
      float v = A.h0[(size_t)((b0 + r) * 2 + A.layer) * 1024 + cz];
      h32[r] = v;
      ushort hi = f2bf(v);
      A.hbh[(b0 + r) * 1024 + cz] = hi;
      A.hbl[(b0 + r) * 1024 + cz] = f2bf(v - bf2f(hi));
    }
  } else {
#pragma unroll
    for (int r = 0; r < 4; ++r) h32[r] = A.h32g[(b0 + r) * 1024 + cz];
  }
  grid.sync();  // covers LDS staging + h init visibility

  const ushort* hhp = A.hbh + (rb * 16 + lr) * 1024 + lkq * 8;
  const ushort* hlp = A.hbl + (rb * 16 + lr) * 1024 + lkq * 8;
  const ushort* rhp = A.rhh + (rb * 16 + lr) * 1024 + lkq * 8;
  const ushort* rlp = A.rhl + (rb * 16 + lr) * 1024 + lkq * 8;
  const ushort* wzl = A.WhzrL + (size_t)(wgc * 16 + lr) * 1024 + lkq * 8;
  const ushort* wrl = A.WhzrL + (size_t)(1024 + wgc * 16 + lr) * 1024 + lkq * 8;

  for (int tl = 0; tl < TC; ++tl) {
    // ---- phase A: z,r = sigmoid(P + h @ Wh{z,r}), 3-term split products ----
    f32x4 az = {}, ar4 = {};
#pragma unroll 4
    for (int k = 0; k < 32; ++k) {
      s16x8 hh = *(const s16x8*)(hhp + k * 32);
      s16x8 hl = *(const s16x8*)(hlp + k * 32);
      s16x8 wz = *(const s16x8*)(&Wz[lr][k * 32 + lkq * 8]);
      s16x8 wr = *(const s16x8*)(&Wr[lr][k * 32 + lkq * 8]);
      az = MFMA(hh, wz, az, 0, 0, 0);
      az = MFMA(hl, wz, az, 0, 0, 0);
      az = MFMA(hh, *(const s16x8*)(wzl + k * 32), az, 0, 0, 0);
      ar4 = MFMA(hh, wr, ar4, 0, 0, 0);
      ar4 = MFMA(hl, wr, ar4, 0, 0, 0);
      ar4 = MFMA(hh, *(const s16x8*)(wrl + k * 32), ar4, 0, 0, 0);
    }
#pragma unroll
    for (int r = 0; r < 4; ++r) {
      int b = b0 + r;
      size_t prow = (size_t)(b * TC + tl) * 3072;
      zv[r] = sigm(A.P[prow + cz] + bzc + az[r]);
      float rv = sigm(A.P[prow + 1024 + cz] + brc + ar4[r]);
      float p = rv * h32[r];
      ushort ph = f2bf(p);
      A.rhh[b * 1024 + cz] = ph;
      A.rhl[b * 1024 + cz] = f2bf(p - bf2f(ph));
    }
    grid.sync();
    // ---- phase B: g = tanh(P + (r*h) @ Whg); h update ----
    f32x4 ag = {};
#pragma unroll 4
    for (int k = 0; k < 32; ++k) {
      s16x8 rh = *(const s16x8*)(rhp + k * 32);
      s16x8 rl = *(const s16x8*)(rlp + k * 32);
      s16x8 wg = *(const s16x8*)(&Wg[lr][k * 32 + lkq * 8]);
      s16x8 wl = *(const s16x8*)(&Wgl[lr][k * 32 + lkq * 8]);
      ag = MFMA(rh, wg, ag, 0, 0, 0);
      ag = MFMA(rl, wg, ag, 0, 0, 0);
      ag = MFMA(rh, wl, ag, 0, 0, 0);
    }
#pragma unroll
    for (int r = 0; r < 4; ++r) {
      int b = b0 + r;
      size_t prow = (size_t)(b * TC + tl) * 3072;
      float g = tanh_(A.P[prow + 2048 + cz] + bgc + ag[r]);
      float hn = zv[r] * h32[r] + (1.f - zv[r]) * g;
      h32[r] = hn;
      ushort hi = f2bf(hn);
      A.hbh[b * 1024 + cz] = hi;
      A.hbl[b * 1024 + cz] = f2bf(hn - bf2f(hi));
      A.Sout[(size_t)(b * TC + tl) * 1024 + cz] = hn;
      if (A.t0 + tl == 511) A.hidout[(size_t)(b * 2 + A.layer) * 1024 + cz] = hn;
    }
    grid.sync();
  }
#pragma unroll
  for (int r = 0; r < 4; ++r) A.h32g[(b0 + r) * 1024 + cz] = h32[r];
}

// ---------- workspace layout (bytes), total ~65.3 MiB ----------
static constexpr size_t OFF_WXT0H   = 0;                                  // [3072][512]
static constexpr size_t OFF_WXT0L   = OFF_WXT0H + 3072ull * 512 * 2;
static constexpr size_t OFF_WHZRT0H = OFF_WXT0L + 3072ull * 512 * 2;      // [2048][1024]
static constexpr size_t OFF_WHZRT0L = OFF_WHZRT0H + 2048ull * 1024 * 2;
static constexpr size_t OFF_WHGT0H  = OFF_WHZRT0L + 2048ull * 1024 * 2;   // [1024][1024]
static constexpr size_t OFF_WHGT0L  = OFF_WHGT0H + 1024ull * 1024 * 2;
static constexpr size_t OFF_WXT1H   = OFF_WHGT0L + 1024ull * 1024 * 2;    // [3072][1024]
static constexpr size_t OFF_WXT1L   = OFF_WXT1H + 3072ull * 1024 * 2;
static constexpr size_t OFF_WHZRT1H = OFF_WXT1L + 3072ull * 1024 * 2;
static constexpr size_t OFF_WHZRT1L = OFF_WHZRT1H + 2048ull * 1024 * 2;
static constexpr size_t OFF_WHGT1H  = OFF_WHZRT1L + 2048ull * 1024 * 2;
static constexpr size_t OFF_WHGT1L  = OFF_WHGT1H + 1024ull * 1024 * 2;
static constexpr size_t OFF_WHYTH   = OFF_WHGT1L + 1024ull * 1024 * 2;    // [512][1024]
static constexpr size_t OFF_WHYTL   = OFF_WHYTH + 512ull * 1024 * 2;
static constexpr size_t OFF_PC      = OFF_WHYTL + 512ull * 1024 * 2;      // [1024][3072] f32
static constexpr size_t OFF_S0      = OFF_PC + 1024ull * 3072 * 4;        // [1024][1024] f32
static constexpr size_t OFF_S1      = OFF_S0 + 1024ull * 1024 * 4;
static constexpr size_t OFF_HBH0    = OFF_S1 + 1024ull * 1024 * 4;        // [64][1024] bf16
static constexpr size_t OFF_HBL0    = OFF_HBH0 + 64ull * 1024 * 2;
static constexpr size_t OFF_HBH1    = OFF_HBL0 + 64ull * 1024 * 2;
static constexpr size_t OFF_HBL1    = OFF_HBH1 + 64ull * 1024 * 2;
static constexpr size_t OFF_H320    = OFF_HBL1 + 64ull * 1024 * 2;        // [64][1024] f32
static constexpr size_t OFF_H321    = OFF_H320 + 64ull * 1024 * 4;
static constexpr size_t OFF_RHH     = OFF_H321 + 64ull * 1024 * 4;        // [64][1024] bf16
static constexpr size_t OFF_RHL     = OFF_RHH + 64ull * 1024 * 2;
static constexpr size_t OFF_END     = OFF_RHL + 64ull * 1024 * 2;

extern "C" void kernel_launch(void* const* d_in, const int* in_sizes, int n_in,
                              void* d_out, int out_size, void* d_ws, size_t ws_size,
                              hipStream_t stream) {
  if (ws_size < OFF_END) return;  // clean fail: zeros => absmax 12.875 signature

  const float* x     = (const float*)d_in[0];
  const float* h0    = (const float*)d_in[1];
  const float* W_xz0 = (const float*)d_in[2];
  const float* W_hz0 = (const float*)d_in[3];
  const float* b_z0  = (const float*)d_in[4];
  const float* W_xr0 = (const float*)d_in[5];
  const float* W_hr0 = (const float*)d_in[6];
  const float* b_r0  = (const float*)d_in[7];
  const float* W_xg0 = (const float*)d_in[8];
  const float* W_hg0 = (const float*)d_in[9];
  const float* b_g0  = (const float*)d_in[10];
  const float* W_xz1 = (const float*)d_in[11];
  const float* W_hz1 = (const float*)d_in[12];
  const float* b_z1  = (const float*)d_in[13];
  const float* W_xr1 = (const float*)d_in[14];
  const float* W_hr1 = (const float*)d_in[15];
  const float* b_r1  = (const float*)d_in[16];
  const float* W_xg1 = (const float*)d_in[17];
  const float* W_hg1 = (const float*)d_in[18];
  const float* b_g1  = (const float*)d_in[19];
  const float* W_hy  = (const float*)d_in[20];
  const float* b_y   = (const float*)d_in[21];

  char* ws = (char*)d_ws;
  float* out_y   = (float*)d_out;                  // [64,512,512]
  float* out_hid = (float*)d_out + 16777216;       // [64,2,1024]

  // weight transpose + hi/lo split: dst[n][k] = src[k][n]
#define TRS(W, OFF_H, OFF_L, kbits, Nsrc, total) \
  tr_cvt_split<<<2048, 256, 0, stream>>>(W, (ushort*)(ws + OFF_H), (ushort*)(ws + OFF_L), kbits, Nsrc, total)
  TRS(W_xz0, OFF_WXT0H,                  OFF_WXT0L,                   9, 1024, 1024 * 512);
  TRS(W_xr0, OFF_WXT0H + 1024ull*512*2,  OFF_WXT0L + 1024ull*512*2,   9, 1024, 1024 * 512);
  TRS(W_xg0, OFF_WXT0H + 2048ull*512*2,  OFF_WXT0L + 2048ull*512*2,   9, 1024, 1024 * 512);
  TRS(W_hz0, OFF_WHZRT0H,                OFF_WHZRT0L,                10, 1024, 1024 * 1024);
  TRS(W_hr0, OFF_WHZRT0H + 1024ull*1024*2, OFF_WHZRT0L + 1024ull*1024*2, 10, 1024, 1024 * 1024);
  TRS(W_hg0, OFF_WHGT0H,                 OFF_WHGT0L,                 10, 1024, 1024 * 1024);
  TRS(W_xz1, OFF_WXT1H,                  OFF_WXT1L,                  10, 1024, 1024 * 1024);
  TRS(W_xr1, OFF_WXT1H + 1024ull*1024*2, OFF_WXT1L + 1024ull*1024*2, 10, 1024, 1024 * 1024);
  TRS(W_xg1, OFF_WXT1H + 2048ull*1024*2, OFF_WXT1L + 2048ull*1024*2, 10, 1024, 1024 * 1024);
  TRS(W_hz1, OFF_WHZRT1H,                OFF_WHZRT1L,                10, 1024, 1024 * 1024);
  TRS(W_hr1, OFF_WHZRT1H + 1024ull*1024*2, OFF_WHZRT1L + 1024ull*1024*2, 10, 1024, 1024 * 1024);
  TRS(W_hg1, OFF_WHGT1H,                 OFF_WHGT1L,                 10, 1024, 1024 * 1024);
  TRS(W_hy,  OFF_WHYTH,                  OFF_WHYTL,                  10, 512,  512 * 1024);
#undef TRS

  float* Pc  = (float*)(ws + OFF_PC);
  float* S0c = (float*)(ws + OFF_S0);
  float* S1c = (float*)(ws + OFF_S1);

  for (int c = 0; c < 512 / TC; ++c) {
    int t0 = c * TC;
    // layer-0 input projections: Pc = x_chunk @ WxT0^T   [1024,3072], K=512
    gemm3<1, 0><<<dim3(8, 24), 256, 0, stream>>>(
        x, (const ushort*)(ws + OFF_WXT0H), (const ushort*)(ws + OFF_WXT0L),
        Pc, nullptr, 1024, 3072, 512, t0);
    // layer-0 scan (cooperative)
    {
      ScanArgs sa;
      sa.P = Pc; sa.bz = b_z0; sa.br = b_r0; sa.bg = b_g0;
      sa.WhzrH = (const ushort*)(ws + OFF_WHZRT0H); sa.WhzrL = (const ushort*)(ws + OFF_WHZRT0L);
      sa.WhgH = (const ushort*)(ws + OFF_WHGT0H);   sa.WhgL = (const ushort*)(ws + OFF_WHGT0L);
      sa.h0 = h0; sa.layer = 0; sa.t0 = t0;
      sa.h32g = (float*)(ws + OFF_H320);
      sa.hbh = (ushort*)(ws + OFF_HBH0); sa.hbl = (ushort*)(ws + OFF_HBL0);
      sa.rhh = (ushort*)(ws + OFF_RHH);  sa.rhl = (ushort*)(ws + OFF_RHL);
      sa.Sout = S0c; sa.hidout = out_hid;
      void* kp[] = { (void*)&sa };
      hipLaunchCooperativeKernel((void*)gru_scan, dim3(NWG_SCAN), dim3(256), kp, 0, stream);
    }
    // layer-1 input projections: Pc = S0c @ WxT1^T  [1024,3072], K=1024
    gemm3<0, 0><<<dim3(8, 24), 256, 0, stream>>>(
        S0c, (const ushort*)(ws + OFF_WXT1H), (const ushort*)(ws + OFF_WXT1L),
        Pc, nullptr, 1024, 3072, 1024, 0);
    // layer-1 scan (cooperative)
    {
      ScanArgs sa;
      sa.P = Pc; sa.bz = b_z1; sa.br = b_r1; sa.bg = b_g1;
      sa.WhzrH = (const ushort*)(ws + OFF_WHZRT1H); sa.WhzrL = (const ushort*)(ws + OFF_WHZRT1L);
      sa.WhgH = (const ushort*)(ws + OFF_WHGT1H);   sa.WhgL = (const ushort*)(ws + OFF_WHGT1L);
      sa.h0 = h0; sa.layer = 1; sa.t0 = t0;
      sa.h32g = (float*)(ws + OFF_H321);
      sa.hbh = (ushort*)(ws + OFF_HBH1); sa.hbl = (ushort*)(ws + OFF_HBL1);
      sa.rhh = (ushort*)(ws + OFF_RHH);  sa.rhl = (ushort*)(ws + OFF_RHL);
      sa.Sout = S1c; sa.hidout = out_hid;
      void* kp[] = { (void*)&sa };
      hipLaunchCooperativeKernel((void*)gru_scan, dim3(NWG_SCAN), dim3(256), kp, 0, stream);
    }
    // output projection: out_y rows = S1c @ WhyT^T + b_y  [1024,512], K=1024
    gemm3<0, 1><<<dim3(8, 4), 256, 0, stream>>>(
        S1c, (const ushort*)(ws + OFF_WHYTH), (const ushort*)(ws + OFF_WHYTL),
        out_y, b_y, 1024, 512, 1024, t0);
  }
}

// Round 5
// 45575.705 us; speedup vs baseline: 1.1736x; 1.1736x over previous
//
#include <hip/hip_runtime.h>

typedef short s16x8 __attribute__((ext_vector_type(8)));
typedef unsigned short us8 __attribute__((ext_vector_type(8)));
typedef float f32x4 __attribute__((ext_vector_type(4)));

#define NWG_SCAN 64
#define TC 16   // time-chunk length

// ---------- helpers ----------
__device__ __forceinline__ ushort f2bf(float f) {
  union { float f; unsigned u; } v; v.f = f;
  unsigned u = v.u;
  u += 0x7fffu + ((u >> 16) & 1u);
  return (ushort)(u >> 16);
}
__device__ __forceinline__ float bf2f(ushort h) {
  union { unsigned u; float f; } v; v.u = ((unsigned)h) << 16; return v.f;
}
__device__ __forceinline__ float sigm(float x) { return 1.f / (1.f + __expf(-x)); }
__device__ __forceinline__ float tanh_(float x) { return 1.f - 2.f / (__expf(2.f * x) + 1.f); }

#define MFMA __builtin_amdgcn_mfma_f32_16x16x32_bf16

// ---------- transpose + split-convert: dst_{hi,lo}[n][k] = split(src[k][n]) ----------
__global__ void tr_cvt_split(const float* __restrict__ src, ushort* __restrict__ hi,
                             ushort* __restrict__ lo, int kbits, int Nsrc, int total) {
  int K1 = (1 << kbits) - 1;
  for (int i = blockIdx.x * blockDim.x + threadIdx.x; i < total; i += gridDim.x * blockDim.x) {
    int n = i >> kbits, k = i & K1;
    float v = src[(size_t)k * Nsrc + n];
    ushort h = f2bf(v);
    hi[i] = h;
    lo[i] = f2bf(v - bf2f(h));
  }
}

// ---------- 3-term split GEMM: C[M,N] f32 = A[M,K] f32 * (Bh+Bl)[N,K]^T ----------
// A is split hi/lo in staging; product = Ah*Bh + Al*Bh + Ah*Bl  (ll term dropped).
// A_SC: chunk-row ar maps to global row (ar>>4)*512 + t0 + (ar&15)  (TC=16).
// C_MODE 0: f32, contiguous chunk rows, no bias. C_MODE 1: f32 + bias, scattered rows.
template <int A_SC, int C_MODE>
__global__ __launch_bounds__(256) void gemm3(
    const float* __restrict__ A, const ushort* __restrict__ Bh, const ushort* __restrict__ Bl,
    float* __restrict__ Cout, const float* __restrict__ bias,
    int M, int N, int K, int t0) {
  __shared__ __align__(16) ushort Ahs[128][72];
  __shared__ __align__(16) ushort Als[128][72];
  __shared__ __align__(16) ushort Bhs[128][72];
  __shared__ __align__(16) ushort Bls[128][72];
  const int bm = blockIdx.x, bn = blockIdx.y;
  const int tid = threadIdx.x, lane = tid & 63;
  const int w = tid >> 6;
  const int wm = (w >> 1) * 64, wn = (w & 1) * 64;
  const int lr = lane & 15;
  const int lk = (lane >> 4) * 8;
  f32x4 acc[4][4] = {};
  for (int k0 = 0; k0 < K; k0 += 64) {
#pragma unroll
    for (int i = 0; i < 4; ++i) {
      int chunk = tid + i * 256;
      int row = chunk >> 3, c = (chunk & 7) * 8;
      int ar = bm * 128 + row;
      size_t grow = A_SC ? ((size_t)(ar >> 4) * 512 + t0 + (ar & 15)) : (size_t)ar;
      const float* srcp = A + grow * K + k0 + c;
      float4 v0 = *(const float4*)(srcp);
      float4 v1 = *(const float4*)(srcp + 4);
      float vv0 = v0.x, vv1 = v0.y, vv2 = v0.z, vv3 = v0.w;
      float vv4 = v1.x, vv5 = v1.y, vv6 = v1.z, vv7 = v1.w;
      us8 uh, ul;
#define SPLIT_E(e, val) { ushort h_ = f2bf(val); uh[e] = h_; ul[e] = f2bf((val) - bf2f(h_)); }
      SPLIT_E(0, vv0) SPLIT_E(1, vv1) SPLIT_E(2, vv2) SPLIT_E(3, vv3)
      SPLIT_E(4, vv4) SPLIT_E(5, vv5) SPLIT_E(6, vv6) SPLIT_E(7, vv7)
#undef SPLIT_E
      *(us8*)(&Ahs[row][c]) = uh;
      *(us8*)(&Als[row][c]) = ul;
      *(int4*)(&Bhs[row][c]) = *(const int4*)(&Bh[(size_t)(bn * 128 + row) * K + k0 + c]);
      *(int4*)(&Bls[row][c]) = *(const int4*)(&Bl[(size_t)(bn * 128 + row) * K + k0 + c]);
    }
    __syncthreads();
#pragma unroll
    for (int kk = 0; kk < 64; kk += 32) {
      s16x8 ah[4], al[4], bh[4], bl[4];
#pragma unroll
      for (int i = 0; i < 4; ++i) {
        ah[i] = *(const s16x8*)(&Ahs[wm + i * 16 + lr][kk + lk]);
        al[i] = *(const s16x8*)(&Als[wm + i * 16 + lr][kk + lk]);
      }
#pragma unroll
      for (int j = 0; j < 4; ++j) {
        bh[j] = *(const s16x8*)(&Bhs[wn + j * 16 + lr][kk + lk]);
        bl[j] = *(const s16x8*)(&Bls[wn + j * 16 + lr][kk + lk]);
      }
#pragma unroll
      for (int i = 0; i < 4; ++i)
#pragma unroll
        for (int j = 0; j < 4; ++j) {
          acc[i][j] = MFMA(ah[i], bh[j], acc[i][j], 0, 0, 0);
          acc[i][j] = MFMA(al[i], bh[j], acc[i][j], 0, 0, 0);
          acc[i][j] = MFMA(ah[i], bl[j], acc[i][j], 0, 0, 0);
        }
    }
    __syncthreads();
  }
#pragma unroll
  for (int i = 0; i < 4; ++i)
#pragma unroll
    for (int j = 0; j < 4; ++j)
#pragma unroll
      for (int r = 0; r < 4; ++r) {
        int lrow = bm * 128 + wm + i * 16 + (lane >> 4) * 4 + r;
        int gcol = bn * 128 + wn + j * 16 + lr;
        float v = acc[i][j][r];
        if (C_MODE == 1) {
          size_t grow = (size_t)(lrow >> 4) * 512 + t0 + (lrow & 15);
          Cout[grow * N + gcol] = v + bias[gcol];
        } else {
          Cout[(size_t)lrow * N + gcol] = v;
        }
      }
}

// ---------- grid barrier (all NWG_SCAN blocks co-resident; proven in r2) ----------
__device__ __forceinline__ void gbar(unsigned* cnt, unsigned* gen) {
  __syncthreads();
  if (threadIdx.x == 0) {
    __threadfence();   // release our writes device-wide
    unsigned g = __hip_atomic_load(gen, __ATOMIC_RELAXED, __HIP_MEMORY_SCOPE_AGENT);
    unsigned a = __hip_atomic_fetch_add(cnt, 1u, __ATOMIC_ACQ_REL, __HIP_MEMORY_SCOPE_AGENT);
    if (a == NWG_SCAN - 1) {
      __hip_atomic_store(cnt, 0u, __ATOMIC_RELAXED, __HIP_MEMORY_SCOPE_AGENT);
      __hip_atomic_store(gen, g + 1u, __ATOMIC_RELEASE, __HIP_MEMORY_SCOPE_AGENT);
    } else {
      while (__hip_atomic_load(gen, __ATOMIC_RELAXED, __HIP_MEMORY_SCOPE_AGENT) == g)
        __builtin_amdgcn_s_sleep(1);
    }
    __threadfence();   // acquire: invalidate so we see other WGs' writes
  }
  __syncthreads();
}

// ---------- persistent GRU scan: one chunk of TC steps for one layer ----------
// 64 WGs x 256 thr. WG wgc owns output cols [wgc*16, +16).
// Full f32-grade precision: P f32; weights hi/lo (hi + Wg_lo in LDS, Wz/Wr lo from L2);
// h and r*h as bf16 hi/lo pairs; h carry in f32.  (identical numerics to r4 PASS)
struct ScanArgs {
  const float* P;             // [64*TC][3072] f32 chunk (z|r|g)
  const float *bz, *br, *bg;
  const ushort *WhzrH, *WhzrL; // [2048][1024] bf16 hi/lo
  const ushort *WhgH, *WhgL;   // [1024][1024] bf16 hi/lo
  const float* h0;
  int layer, t0;
  float* h32g;                // [64][1024] f32 carry
  ushort *hbh, *hbl;          // [64][1024] bf16 hi/lo of h
  ushort *rhh, *rhl;          // [64][1024] bf16 hi/lo of r*h
  float* Sout;                // [64*TC][1024] f32 chunk
  float* hidout;              // [64][2][1024] f32
  unsigned *barc, *barg;      // grid barrier state
};

__global__ __launch_bounds__(256) void gru_scan(ScanArgs A) {
  __shared__ __align__(16) ushort Wz[16][1032];
  __shared__ __align__(16) ushort Wr[16][1032];
  __shared__ __align__(16) ushort Wg[16][1032];
  __shared__ __align__(16) ushort Wgl[16][1032];
  const int tid = threadIdx.x, lane = tid & 63;
  const int rb = tid >> 6;                    // rowblock 0..3
  const int wgc = blockIdx.x;                 // col slice 0..63
  const int lr = lane & 15, lkq = lane >> 4;
  const int cz = wgc * 16 + lr;               // this lane's output column

  // stage weight hi-slices (+ Wg lo) into LDS
  {
    const ushort* srcz = A.WhzrH + (size_t)(wgc * 16) * 1024;
    const ushort* srcr = A.WhzrH + (size_t)(1024 + wgc * 16) * 1024;
    const ushort* srcg = A.WhgH + (size_t)(wgc * 16) * 1024;
    const ushort* srcgl = A.WhgL + (size_t)(wgc * 16) * 1024;
#pragma unroll
    for (int j = 0; j < 8; ++j) {
      int id = tid + j * 256;
      int row = id >> 7, ko = (id & 127) * 8;
      *(int4*)(&Wz[row][ko]) = *(const int4*)(srcz + row * 1024 + ko);
      *(int4*)(&Wr[row][ko]) = *(const int4*)(srcr + row * 1024 + ko);
      *(int4*)(&Wg[row][ko]) = *(const int4*)(srcg + row * 1024 + ko);
      *(int4*)(&Wgl[row][ko]) = *(const int4*)(srcgl + row * 1024 + ko);
    }
  }

  const int b0 = rb * 16 + lkq * 4;
  float h32[4], zv[4];
  const float bzc = A.bz[cz], brc = A.br[cz], bgc = A.bg[cz];

  if (A.t0 == 0) {
#pragma unroll
    for (int r = 0; r < 4; ++r) {
      float v = A.h0[(size_t)((b0 + r) * 2 + A.layer) * 1024 + cz];
      h32[r] = v;
      ushort hi = f2bf(v);
      A.hbh[(b0 + r) * 1024 + cz] = hi;
      A.hbl[(b0 + r) * 1024 + cz] = f2bf(v - bf2f(hi));
    }
  } else {
#pragma unroll
    for (int r = 0; r < 4; ++r) h32[r] = A.h32g[(b0 + r) * 1024 + cz];
  }
  gbar(A.barc, A.barg);  // covers LDS staging + h init visibility

  const ushort* hhp = A.hbh + (rb * 16 + lr) * 1024 + lkq * 8;
  const ushort* hlp = A.hbl + (rb * 16 + lr) * 1024 + lkq * 8;
  const ushort* rhp = A.rhh + (rb * 16 + lr) * 1024 + lkq * 8;
  const ushort* rlp = A.rhl + (rb * 16 + lr) * 1024 + lkq * 8;
  const ushort* wzl = A.WhzrL + (size_t)(wgc * 16 + lr) * 1024 + lkq * 8;
  const ushort* wrl = A.WhzrL + (size_t)(1024 + wgc * 16 + lr) * 1024 + lkq * 8;

  for (int tl = 0; tl < TC; ++tl) {
    // ---- phase A: z,r = sigmoid(P + h @ Wh{z,r}), 3-term split products ----
    f32x4 az = {}, ar4 = {};
#pragma unroll 4
    for (int k = 0; k < 32; ++k) {
      s16x8 hh = *(const s16x8*)(hhp + k * 32);
      s16x8 hl = *(const s16x8*)(hlp + k * 32);
      s16x8 wz = *(const s16x8*)(&Wz[lr][k * 32 + lkq * 8]);
      s16x8 wr = *(const s16x8*)(&Wr[lr][k * 32 + lkq * 8]);
      az = MFMA(hh, wz, az, 0, 0, 0);
      az = MFMA(hl, wz, az, 0, 0, 0);
      az = MFMA(hh, *(const s16x8*)(wzl + k * 32), az, 0, 0, 0);
      ar4 = MFMA(hh, wr, ar4, 0, 0, 0);
      ar4 = MFMA(hl, wr, ar4, 0, 0, 0);
      ar4 = MFMA(hh, *(const s16x8*)(wrl + k * 32), ar4, 0, 0, 0);
    }
#pragma unroll
    for (int r = 0; r < 4; ++r) {
      int b = b0 + r;
      size_t prow = (size_t)(b * TC + tl) * 3072;
      zv[r] = sigm(A.P[prow + cz] + bzc + az[r]);
      float rv = sigm(A.P[prow + 1024 + cz] + brc + ar4[r]);
      float p = rv * h32[r];
      ushort ph = f2bf(p);
      A.rhh[b * 1024 + cz] = ph;
      A.rhl[b * 1024 + cz] = f2bf(p - bf2f(ph));
    }
    gbar(A.barc, A.barg);
    // ---- phase B: g = tanh(P + (r*h) @ Whg); h update ----
    f32x4 ag = {};
#pragma unroll 4
    for (int k = 0; k < 32; ++k) {
      s16x8 rh = *(const s16x8*)(rhp + k * 32);
      s16x8 rl = *(const s16x8*)(rlp + k * 32);
      s16x8 wg = *(const s16x8*)(&Wg[lr][k * 32 + lkq * 8]);
      s16x8 wl = *(const s16x8*)(&Wgl[lr][k * 32 + lkq * 8]);
      ag = MFMA(rh, wg, ag, 0, 0, 0);
      ag = MFMA(rl, wg, ag, 0, 0, 0);
      ag = MFMA(rh, wl, ag, 0, 0, 0);
    }
#pragma unroll
    for (int r = 0; r < 4; ++r) {
      int b = b0 + r;
      size_t prow = (size_t)(b * TC + tl) * 3072;
      float g = tanh_(A.P[prow + 2048 + cz] + bgc + ag[r]);
      float hn = zv[r] * h32[r] + (1.f - zv[r]) * g;
      h32[r] = hn;
      ushort hi = f2bf(hn);
      A.hbh[b * 1024 + cz] = hi;
      A.hbl[b * 1024 + cz] = f2bf(hn - bf2f(hi));
      A.Sout[(size_t)(b * TC + tl) * 1024 + cz] = hn;
      if (A.t0 + tl == 511) A.hidout[(size_t)(b * 2 + A.layer) * 1024 + cz] = hn;
    }
    gbar(A.barc, A.barg);
  }
#pragma unroll
  for (int r = 0; r < 4; ++r) A.h32g[(b0 + r) * 1024 + cz] = h32[r];
}

// ---------- workspace layout (bytes), total ~65.3 MiB ----------
static constexpr size_t OFF_WXT0H   = 0;                                  // [3072][512]
static constexpr size_t OFF_WXT0L   = OFF_WXT0H + 3072ull * 512 * 2;
static constexpr size_t OFF_WHZRT0H = OFF_WXT0L + 3072ull * 512 * 2;      // [2048][1024]
static constexpr size_t OFF_WHZRT0L = OFF_WHZRT0H + 2048ull * 1024 * 2;
static constexpr size_t OFF_WHGT0H  = OFF_WHZRT0L + 2048ull * 1024 * 2;   // [1024][1024]
static constexpr size_t OFF_WHGT0L  = OFF_WHGT0H + 1024ull * 1024 * 2;
static constexpr size_t OFF_WXT1H   = OFF_WHGT0L + 1024ull * 1024 * 2;    // [3072][1024]
static constexpr size_t OFF_WXT1L   = OFF_WXT1H + 3072ull * 1024 * 2;
static constexpr size_t OFF_WHZRT1H = OFF_WXT1L + 3072ull * 1024 * 2;
static constexpr size_t OFF_WHZRT1L = OFF_WHZRT1H + 2048ull * 1024 * 2;
static constexpr size_t OFF_WHGT1H  = OFF_WHZRT1L + 2048ull * 1024 * 2;
static constexpr size_t OFF_WHGT1L  = OFF_WHGT1H + 1024ull * 1024 * 2;
static constexpr size_t OFF_WHYTH   = OFF_WHGT1L + 1024ull * 1024 * 2;    // [512][1024]
static constexpr size_t OFF_WHYTL   = OFF_WHYTH + 512ull * 1024 * 2;
static constexpr size_t OFF_PC      = OFF_WHYTL + 512ull * 1024 * 2;      // [1024][3072] f32
static constexpr size_t OFF_S0      = OFF_PC + 1024ull * 3072 * 4;        // [1024][1024] f32
static constexpr size_t OFF_S1      = OFF_S0 + 1024ull * 1024 * 4;
static constexpr size_t OFF_HBH0    = OFF_S1 + 1024ull * 1024 * 4;        // [64][1024] bf16
static constexpr size_t OFF_HBL0    = OFF_HBH0 + 64ull * 1024 * 2;
static constexpr size_t OFF_HBH1    = OFF_HBL0 + 64ull * 1024 * 2;
static constexpr size_t OFF_HBL1    = OFF_HBH1 + 64ull * 1024 * 2;
static constexpr size_t OFF_H320    = OFF_HBL1 + 64ull * 1024 * 2;        // [64][1024] f32
static constexpr size_t OFF_H321    = OFF_H320 + 64ull * 1024 * 4;
static constexpr size_t OFF_RHH     = OFF_H321 + 64ull * 1024 * 4;        // [64][1024] bf16
static constexpr size_t OFF_RHL     = OFF_RHH + 64ull * 1024 * 2;
static constexpr size_t OFF_BAR     = OFF_RHL + 64ull * 1024 * 2;
static constexpr size_t OFF_END     = OFF_BAR + 128;

extern "C" void kernel_launch(void* const* d_in, const int* in_sizes, int n_in,
                              void* d_out, int out_size, void* d_ws, size_t ws_size,
                              hipStream_t stream) {
  if (ws_size < OFF_END) return;  // clean fail: zeros => absmax 12.875 signature

  const float* x     = (const float*)d_in[0];
  const float* h0    = (const float*)d_in[1];
  const float* W_xz0 = (const float*)d_in[2];
  const float* W_hz0 = (const float*)d_in[3];
  const float* b_z0  = (const float*)d_in[4];
  const float* W_xr0 = (const float*)d_in[5];
  const float* W_hr0 = (const float*)d_in[6];
  const float* b_r0  = (const float*)d_in[7];
  const float* W_xg0 = (const float*)d_in[8];
  const float* W_hg0 = (const float*)d_in[9];
  const float* b_g0  = (const float*)d_in[10];
  const float* W_xz1 = (const float*)d_in[11];
  const float* W_hz1 = (const float*)d_in[12];
  const float* b_z1  = (const float*)d_in[13];
  const float* W_xr1 = (const float*)d_in[14];
  const float* W_hr1 = (const float*)d_in[15];
  const float* b_r1  = (const float*)d_in[16];
  const float* W_xg1 = (const float*)d_in[17];
  const float* W_hg1 = (const float*)d_in[18];
  const float* b_g1  = (const float*)d_in[19];
  const float* W_hy  = (const float*)d_in[20];
  const float* b_y   = (const float*)d_in[21];

  char* ws = (char*)d_ws;
  float* out_y   = (float*)d_out;                  // [64,512,512]
  float* out_hid = (float*)d_out + 16777216;       // [64,2,1024]
  unsigned* barc = (unsigned*)(ws + OFF_BAR);
  unsigned* barg = barc + 1;

  hipMemsetAsync(barc, 0, 128, stream);

  // weight transpose + hi/lo split: dst[n][k] = src[k][n]
#define TRS(W, OFF_H, OFF_L, kbits, Nsrc, total) \
  tr_cvt_split<<<2048, 256, 0, stream>>>(W, (ushort*)(ws + OFF_H), (ushort*)(ws + OFF_L), kbits, Nsrc, total)
  TRS(W_xz0, OFF_WXT0H,                  OFF_WXT0L,                   9, 1024, 1024 * 512);
  TRS(W_xr0, OFF_WXT0H + 1024ull*512*2,  OFF_WXT0L + 1024ull*512*2,   9, 1024, 1024 * 512);
  TRS(W_xg0, OFF_WXT0H + 2048ull*512*2,  OFF_WXT0L + 2048ull*512*2,   9, 1024, 1024 * 512);
  TRS(W_hz0, OFF_WHZRT0H,                OFF_WHZRT0L,                10, 1024, 1024 * 1024);
  TRS(W_hr0, OFF_WHZRT0H + 1024ull*1024*2, OFF_WHZRT0L + 1024ull*1024*2, 10, 1024, 1024 * 1024);
  TRS(W_hg0, OFF_WHGT0H,                 OFF_WHGT0L,                 10, 1024, 1024 * 1024);
  TRS(W_xz1, OFF_WXT1H,                  OFF_WXT1L,                  10, 1024, 1024 * 1024);
  TRS(W_xr1, OFF_WXT1H + 1024ull*1024*2, OFF_WXT1L + 1024ull*1024*2, 10, 1024, 1024 * 1024);
  TRS(W_xg1, OFF_WXT1H + 2048ull*1024*2, OFF_WXT1L + 2048ull*1024*2, 10, 1024, 1024 * 1024);
  TRS(W_hz1, OFF_WHZRT1H,                OFF_WHZRT1L,                10, 1024, 1024 * 1024);
  TRS(W_hr1, OFF_WHZRT1H + 1024ull*1024*2, OFF_WHZRT1L + 1024ull*1024*2, 10, 1024, 1024 * 1024);
  TRS(W_hg1, OFF_WHGT1H,                 OFF_WHGT1L,                 10, 1024, 1024 * 1024);
  TRS(W_hy,  OFF_WHYTH,                  OFF_WHYTL,                  10, 512,  512 * 1024);
#undef TRS

  float* Pc  = (float*)(ws + OFF_PC);
  float* S0c = (float*)(ws + OFF_S0);
  float* S1c = (float*)(ws + OFF_S1);

  for (int c = 0; c < 512 / TC; ++c) {
    int t0 = c * TC;
    // layer-0 input projections: Pc = x_chunk @ WxT0^T   [1024,3072], K=512
    gemm3<1, 0><<<dim3(8, 24), 256, 0, stream>>>(
        x, (const ushort*)(ws + OFF_WXT0H), (const ushort*)(ws + OFF_WXT0L),
        Pc, nullptr, 1024, 3072, 512, t0);
    // layer-0 scan
    {
      ScanArgs sa;
      sa.P = Pc; sa.bz = b_z0; sa.br = b_r0; sa.bg = b_g0;
      sa.WhzrH = (const ushort*)(ws + OFF_WHZRT0H); sa.WhzrL = (const ushort*)(ws + OFF_WHZRT0L);
      sa.WhgH = (const ushort*)(ws + OFF_WHGT0H);   sa.WhgL = (const ushort*)(ws + OFF_WHGT0L);
      sa.h0 = h0; sa.layer = 0; sa.t0 = t0;
      sa.h32g = (float*)(ws + OFF_H320);
      sa.hbh = (ushort*)(ws + OFF_HBH0); sa.hbl = (ushort*)(ws + OFF_HBL0);
      sa.rhh = (ushort*)(ws + OFF_RHH);  sa.rhl = (ushort*)(ws + OFF_RHL);
      sa.Sout = S0c; sa.hidout = out_hid;
      sa.barc = barc; sa.barg = barg;
      gru_scan<<<NWG_SCAN, 256, 0, stream>>>(sa);
    }
    // layer-1 input projections: Pc = S0c @ WxT1^T  [1024,3072], K=1024
    gemm3<0, 0><<<dim3(8, 24), 256, 0, stream>>>(
        S0c, (const ushort*)(ws + OFF_WXT1H), (const ushort*)(ws + OFF_WXT1L),
        Pc, nullptr, 1024, 3072, 1024, 0);
    // layer-1 scan
    {
      ScanArgs sa;
      sa.P = Pc; sa.bz = b_z1; sa.br = b_r1; sa.bg = b_g1;
      sa.WhzrH = (const ushort*)(ws + OFF_WHZRT1H); sa.WhzrL = (const ushort*)(ws + OFF_WHZRT1L);
      sa.WhgH = (const ushort*)(ws + OFF_WHGT1H);   sa.WhgL = (const ushort*)(ws + OFF_WHGT1L);
      sa.h0 = h0; sa.layer = 1; sa.t0 = t0;
      sa.h32g = (float*)(ws + OFF_H321);
      sa.hbh = (ushort*)(ws + OFF_HBH1); sa.hbl = (ushort*)(ws + OFF_HBL1);
      sa.rhh = (ushort*)(ws + OFF_RHH);  sa.rhl = (ushort*)(ws + OFF_RHL);
      sa.Sout = S1c; sa.hidout = out_hid;
      sa.barc = barc; sa.barg = barg;
      gru_scan<<<NWG_SCAN, 256, 0, stream>>>(sa);
    }
    // output projection: out_y rows = S1c @ WhyT^T + b_y  [1024,512], K=1024
    gemm3<0, 1><<<dim3(8, 4), 256, 0, stream>>>(
        S1c, (const ushort*)(ws + OFF_WHYTH), (const ushort*)(ws + OFF_WHYTL),
        out_y, b_y, 1024, 512, 1024, t0);
  }
}

// Round 6
// 40454.465 us; speedup vs baseline: 1.3221x; 1.1266x over previous
//
#include <hip/hip_runtime.h>

typedef short s16x8 __attribute__((ext_vector_type(8)));
typedef unsigned short us8 __attribute__((ext_vector_type(8)));
typedef float f32x4 __attribute__((ext_vector_type(4)));

#define NWG_SCAN 64
#define TC 16   // time-chunk length

// ---------- helpers ----------
__device__ __forceinline__ ushort f2bf(float f) {
  union { float f; unsigned u; } v; v.f = f;
  unsigned u = v.u;
  u += 0x7fffu + ((u >> 16) & 1u);
  return (ushort)(u >> 16);
}
__device__ __forceinline__ float bf2f(ushort h) {
  union { unsigned u; float f; } v; v.u = ((unsigned)h) << 16; return v.f;
}
__device__ __forceinline__ float sigm(float x) { return 1.f / (1.f + __expf(-x)); }
__device__ __forceinline__ float tanh_(float x) { return 1.f - 2.f / (__expf(2.f * x) + 1.f); }

#define MFMA __builtin_amdgcn_mfma_f32_16x16x32_bf16

// device-coherent 16B load: bypasses L1/L2, reads at the device coherence point.
// Caller MUST s_waitcnt vmcnt(0) before consuming (batched below, rule #18 pattern).
__device__ __forceinline__ s16x8 ld_sc16(const ushort* p) {
  s16x8 v;
  asm volatile("global_load_dwordx4 %0, %1, off sc0 sc1" : "=v"(v) : "v"(p));
  return v;
}
// device-coherent 2B store (write-through; visible device-wide once vmcnt retires)
__device__ __forceinline__ void st_sc2(ushort* p, ushort x) {
  unsigned v = x;
  asm volatile("global_store_short %0, %1, off sc0 sc1" :: "v"(p), "v"(v) : "memory");
}

// ---------- transpose + split-convert: dst_{hi,lo}[n][k] = split(src[k][n]) ----------
__global__ void tr_cvt_split(const float* __restrict__ src, ushort* __restrict__ hi,
                             ushort* __restrict__ lo, int kbits, int Nsrc, int total) {
  int K1 = (1 << kbits) - 1;
  for (int i = blockIdx.x * blockDim.x + threadIdx.x; i < total; i += gridDim.x * blockDim.x) {
    int n = i >> kbits, k = i & K1;
    float v = src[(size_t)k * Nsrc + n];
    ushort h = f2bf(v);
    hi[i] = h;
    lo[i] = f2bf(v - bf2f(h));
  }
}

// ---------- 3-term split GEMM: C[M,N] f32 = A[M,K] f32 * (Bh+Bl)[N,K]^T ----------
template <int A_SC, int C_MODE>
__global__ __launch_bounds__(256) void gemm3(
    const float* __restrict__ A, const ushort* __restrict__ Bh, const ushort* __restrict__ Bl,
    float* __restrict__ Cout, const float* __restrict__ bias,
    int M, int N, int K, int t0) {
  __shared__ __align__(16) ushort Ahs[128][72];
  __shared__ __align__(16) ushort Als[128][72];
  __shared__ __align__(16) ushort Bhs[128][72];
  __shared__ __align__(16) ushort Bls[128][72];
  const int bm = blockIdx.x, bn = blockIdx.y;
  const int tid = threadIdx.x, lane = tid & 63;
  const int w = tid >> 6;
  const int wm = (w >> 1) * 64, wn = (w & 1) * 64;
  const int lr = lane & 15;
  const int lk = (lane >> 4) * 8;
  f32x4 acc[4][4] = {};
  for (int k0 = 0; k0 < K; k0 += 64) {
#pragma unroll
    for (int i = 0; i < 4; ++i) {
      int chunk = tid + i * 256;
      int row = chunk >> 3, c = (chunk & 7) * 8;
      int ar = bm * 128 + row;
      size_t grow = A_SC ? ((size_t)(ar >> 4) * 512 + t0 + (ar & 15)) : (size_t)ar;
      const float* srcp = A + grow * K + k0 + c;
      float4 v0 = *(const float4*)(srcp);
      float4 v1 = *(const float4*)(srcp + 4);
      float vv0 = v0.x, vv1 = v0.y, vv2 = v0.z, vv3 = v0.w;
      float vv4 = v1.x, vv5 = v1.y, vv6 = v1.z, vv7 = v1.w;
      us8 uh, ul;
#define SPLIT_E(e, val) { ushort h_ = f2bf(val); uh[e] = h_; ul[e] = f2bf((val) - bf2f(h_)); }
      SPLIT_E(0, vv0) SPLIT_E(1, vv1) SPLIT_E(2, vv2) SPLIT_E(3, vv3)
      SPLIT_E(4, vv4) SPLIT_E(5, vv5) SPLIT_E(6, vv6) SPLIT_E(7, vv7)
#undef SPLIT_E
      *(us8*)(&Ahs[row][c]) = uh;
      *(us8*)(&Als[row][c]) = ul;
      *(int4*)(&Bhs[row][c]) = *(const int4*)(&Bh[(size_t)(bn * 128 + row) * K + k0 + c]);
      *(int4*)(&Bls[row][c]) = *(const int4*)(&Bl[(size_t)(bn * 128 + row) * K + k0 + c]);
    }
    __syncthreads();
#pragma unroll
    for (int kk = 0; kk < 64; kk += 32) {
      s16x8 ah[4], al[4], bh[4], bl[4];
#pragma unroll
      for (int i = 0; i < 4; ++i) {
        ah[i] = *(const s16x8*)(&Ahs[wm + i * 16 + lr][kk + lk]);
        al[i] = *(const s16x8*)(&Als[wm + i * 16 + lr][kk + lk]);
      }
#pragma unroll
      for (int j = 0; j < 4; ++j) {
        bh[j] = *(const s16x8*)(&Bhs[wn + j * 16 + lr][kk + lk]);
        bl[j] = *(const s16x8*)(&Bls[wn + j * 16 + lr][kk + lk]);
      }
#pragma unroll
      for (int i = 0; i < 4; ++i)
#pragma unroll
        for (int j = 0; j < 4; ++j) {
          acc[i][j] = MFMA(ah[i], bh[j], acc[i][j], 0, 0, 0);
          acc[i][j] = MFMA(al[i], bh[j], acc[i][j], 0, 0, 0);
          acc[i][j] = MFMA(ah[i], bl[j], acc[i][j], 0, 0, 0);
        }
    }
    __syncthreads();
  }
#pragma unroll
  for (int i = 0; i < 4; ++i)
#pragma unroll
    for (int j = 0; j < 4; ++j)
#pragma unroll
      for (int r = 0; r < 4; ++r) {
        int lrow = bm * 128 + wm + i * 16 + (lane >> 4) * 4 + r;
        int gcol = bn * 128 + wn + j * 16 + lr;
        float v = acc[i][j][r];
        if (C_MODE == 1) {
          size_t grow = (size_t)(lrow >> 4) * 512 + t0 + (lrow & 15);
          Cout[grow * N + gcol] = v + bias[gcol];
        } else {
          Cout[(size_t)lrow * N + gcol] = v;
        }
      }
}

// ---------- fence-free grid barrier (monotonic counter; comm data is sc0sc1) ----------
// Correctness: all comm stores are write-through (sc0 sc1); vmcnt(0)+__syncthreads
// drains them to the coherence point before tid0 announces arrival. Readers use
// sc0 sc1 loads, so no L2 invalidation (no __threadfence / buffer_inv walk) needed.
__device__ __forceinline__ void gbar(unsigned* cnt, unsigned target) {
  asm volatile("s_waitcnt vmcnt(0)" ::: "memory");
  __syncthreads();
  if (threadIdx.x == 0) {
    __hip_atomic_fetch_add(cnt, 1u, __ATOMIC_RELAXED, __HIP_MEMORY_SCOPE_AGENT);
    while (__hip_atomic_load(cnt, __ATOMIC_RELAXED, __HIP_MEMORY_SCOPE_AGENT) < target)
      __builtin_amdgcn_s_sleep(1);
  }
  __syncthreads();
}

// ---------- persistent GRU scan: one chunk of TC steps for one layer ----------
// Numerics identical to r4/r5 PASS: P f32; weights hi/lo; h & r*h bf16 hi/lo; h carry f32.
struct ScanArgs {
  const float* P;             // [64*TC][3072] f32 chunk (z|r|g)
  const float *bz, *br, *bg;
  const ushort *WhzrH, *WhzrL; // [2048][1024] bf16 hi/lo
  const ushort *WhgH, *WhgL;   // [1024][1024] bf16 hi/lo
  const float* h0;
  int layer, t0;
  float* h32g;                // [64][1024] f32 carry
  ushort *hbh, *hbl;          // [64][1024] bf16 hi/lo of h   (sc0sc1 comm)
  ushort *rhh, *rhl;          // [64][1024] bf16 hi/lo of r*h (sc0sc1 comm)
  float* Sout;                // [64*TC][1024] f32 chunk
  float* hidout;              // [64][2][1024] f32
  unsigned* barc;             // monotonic barrier counter
  unsigned bar_base;          // per-launch base (launch_idx * 33 * 64)
};

__global__ __launch_bounds__(256) void gru_scan(ScanArgs A) {
  __shared__ __align__(16) ushort Wz[16][1032];
  __shared__ __align__(16) ushort Wr[16][1032];
  __shared__ __align__(16) ushort Wg[16][1032];
  __shared__ __align__(16) ushort Wgl[16][1032];
  const int tid = threadIdx.x, lane = tid & 63;
  const int rb = tid >> 6;                    // rowblock 0..3
  const int wgc = blockIdx.x;                 // col slice 0..63
  const int lr = lane & 15, lkq = lane >> 4;
  const int cz = wgc * 16 + lr;               // this lane's output column
  unsigned tgt = A.bar_base;

  // stage weight hi-slices (+ Wg lo) into LDS
  {
    const ushort* srcz = A.WhzrH + (size_t)(wgc * 16) * 1024;
    const ushort* srcr = A.WhzrH + (size_t)(1024 + wgc * 16) * 1024;
    const ushort* srcg = A.WhgH + (size_t)(wgc * 16) * 1024;
    const ushort* srcgl = A.WhgL + (size_t)(wgc * 16) * 1024;
#pragma unroll
    for (int j = 0; j < 8; ++j) {
      int id = tid + j * 256;
      int row = id >> 7, ko = (id & 127) * 8;
      *(int4*)(&Wz[row][ko]) = *(const int4*)(srcz + row * 1024 + ko);
      *(int4*)(&Wr[row][ko]) = *(const int4*)(srcr + row * 1024 + ko);
      *(int4*)(&Wg[row][ko]) = *(const int4*)(srcg + row * 1024 + ko);
      *(int4*)(&Wgl[row][ko]) = *(const int4*)(srcgl + row * 1024 + ko);
    }
  }

  const int b0 = rb * 16 + lkq * 4;
  float h32[4], zv[4];
  const float bzc = A.bz[cz], brc = A.br[cz], bgc = A.bg[cz];

  if (A.t0 == 0) {
#pragma unroll
    for (int r = 0; r < 4; ++r) {
      float v = A.h0[(size_t)((b0 + r) * 2 + A.layer) * 1024 + cz];
      h32[r] = v;
      ushort hi = f2bf(v);
      st_sc2(&A.hbh[(b0 + r) * 1024 + cz], hi);
      st_sc2(&A.hbl[(b0 + r) * 1024 + cz], f2bf(v - bf2f(hi)));
    }
  } else {
#pragma unroll
    for (int r = 0; r < 4; ++r) h32[r] = A.h32g[(b0 + r) * 1024 + cz];
  }
  tgt += 64; gbar(A.barc, tgt);   // covers LDS staging + h init visibility

  const ushort* hhp = A.hbh + (rb * 16 + lr) * 1024 + lkq * 8;
  const ushort* hlp = A.hbl + (rb * 16 + lr) * 1024 + lkq * 8;
  const ushort* rhp = A.rhh + (rb * 16 + lr) * 1024 + lkq * 8;
  const ushort* rlp = A.rhl + (rb * 16 + lr) * 1024 + lkq * 8;
  const ushort* wzl = A.WhzrL + (size_t)(wgc * 16 + lr) * 1024 + lkq * 8;
  const ushort* wrl = A.WhzrL + (size_t)(1024 + wgc * 16 + lr) * 1024 + lkq * 8;

  for (int tl = 0; tl < TC; ++tl) {
    // ---- phase A: z,r = sigmoid(P + h @ Wh{z,r}), 3-term split products ----
    f32x4 az = {}, ar4 = {};
#pragma unroll
    for (int kb = 0; kb < 4; ++kb) {
      s16x8 hhv[8], hlv[8];
#pragma unroll
      for (int e = 0; e < 8; ++e) {
        hhv[e] = ld_sc16(hhp + (kb * 8 + e) * 32);
        hlv[e] = ld_sc16(hlp + (kb * 8 + e) * 32);
      }
      asm volatile("s_waitcnt vmcnt(0)" ::: "memory");
      __builtin_amdgcn_sched_barrier(0);
#pragma unroll
      for (int e = 0; e < 8; ++e) {
        int k = kb * 8 + e;
        s16x8 wz = *(const s16x8*)(&Wz[lr][k * 32 + lkq * 8]);
        s16x8 wr = *(const s16x8*)(&Wr[lr][k * 32 + lkq * 8]);
        az = MFMA(hhv[e], wz, az, 0, 0, 0);
        az = MFMA(hlv[e], wz, az, 0, 0, 0);
        az = MFMA(hhv[e], *(const s16x8*)(wzl + k * 32), az, 0, 0, 0);
        ar4 = MFMA(hhv[e], wr, ar4, 0, 0, 0);
        ar4 = MFMA(hlv[e], wr, ar4, 0, 0, 0);
        ar4 = MFMA(hhv[e], *(const s16x8*)(wrl + k * 32), ar4, 0, 0, 0);
      }
    }
#pragma unroll
    for (int r = 0; r < 4; ++r) {
      int b = b0 + r;
      size_t prow = (size_t)(b * TC + tl) * 3072;
      zv[r] = sigm(A.P[prow + cz] + bzc + az[r]);
      float rv = sigm(A.P[prow + 1024 + cz] + brc + ar4[r]);
      float p = rv * h32[r];
      ushort ph = f2bf(p);
      st_sc2(&A.rhh[b * 1024 + cz], ph);
      st_sc2(&A.rhl[b * 1024 + cz], f2bf(p - bf2f(ph)));
    }
    tgt += 64; gbar(A.barc, tgt);
    // ---- phase B: g = tanh(P + (r*h) @ Whg); h update ----
    f32x4 ag = {};
#pragma unroll
    for (int kb = 0; kb < 4; ++kb) {
      s16x8 rhv[8], rlv[8];
#pragma unroll
      for (int e = 0; e < 8; ++e) {
        rhv[e] = ld_sc16(rhp + (kb * 8 + e) * 32);
        rlv[e] = ld_sc16(rlp + (kb * 8 + e) * 32);
      }
      asm volatile("s_waitcnt vmcnt(0)" ::: "memory");
      __builtin_amdgcn_sched_barrier(0);
#pragma unroll
      for (int e = 0; e < 8; ++e) {
        int k = kb * 8 + e;
        s16x8 wg = *(const s16x8*)(&Wg[lr][k * 32 + lkq * 8]);
        s16x8 wl = *(const s16x8*)(&Wgl[lr][k * 32 + lkq * 8]);
        ag = MFMA(rhv[e], wg, ag, 0, 0, 0);
        ag = MFMA(rlv[e], wg, ag, 0, 0, 0);
        ag = MFMA(rhv[e], wl, ag, 0, 0, 0);
      }
    }
#pragma unroll
    for (int r = 0; r < 4; ++r) {
      int b = b0 + r;
      size_t prow = (size_t)(b * TC + tl) * 3072;
      float g = tanh_(A.P[prow + 2048 + cz] + bgc + ag[r]);
      float hn = zv[r] * h32[r] + (1.f - zv[r]) * g;
      h32[r] = hn;
      ushort hi = f2bf(hn);
      st_sc2(&A.hbh[b * 1024 + cz], hi);
      st_sc2(&A.hbl[b * 1024 + cz], f2bf(hn - bf2f(hi)));
      A.Sout[(size_t)(b * TC + tl) * 1024 + cz] = hn;
      if (A.t0 + tl == 511) A.hidout[(size_t)(b * 2 + A.layer) * 1024 + cz] = hn;
    }
    tgt += 64; gbar(A.barc, tgt);
  }
#pragma unroll
  for (int r = 0; r < 4; ++r) A.h32g[(b0 + r) * 1024 + cz] = h32[r];
}

// ---------- workspace layout (bytes), total ~65.3 MiB ----------
static constexpr size_t OFF_WXT0H   = 0;                                  // [3072][512]
static constexpr size_t OFF_WXT0L   = OFF_WXT0H + 3072ull * 512 * 2;
static constexpr size_t OFF_WHZRT0H = OFF_WXT0L + 3072ull * 512 * 2;      // [2048][1024]
static constexpr size_t OFF_WHZRT0L = OFF_WHZRT0H + 2048ull * 1024 * 2;
static constexpr size_t OFF_WHGT0H  = OFF_WHZRT0L + 2048ull * 1024 * 2;   // [1024][1024]
static constexpr size_t OFF_WHGT0L  = OFF_WHGT0H + 1024ull * 1024 * 2;
static constexpr size_t OFF_WXT1H   = OFF_WHGT0L + 1024ull * 1024 * 2;    // [3072][1024]
static constexpr size_t OFF_WXT1L   = OFF_WXT1H + 3072ull * 1024 * 2;
static constexpr size_t OFF_WHZRT1H = OFF_WXT1L + 3072ull * 1024 * 2;
static constexpr size_t OFF_WHZRT1L = OFF_WHZRT1H + 2048ull * 1024 * 2;
static constexpr size_t OFF_WHGT1H  = OFF_WHZRT1L + 2048ull * 1024 * 2;
static constexpr size_t OFF_WHGT1L  = OFF_WHGT1H + 1024ull * 1024 * 2;
static constexpr size_t OFF_WHYTH   = OFF_WHGT1L + 1024ull * 1024 * 2;    // [512][1024]
static constexpr size_t OFF_WHYTL   = OFF_WHYTH + 512ull * 1024 * 2;
static constexpr size_t OFF_PC      = OFF_WHYTL + 512ull * 1024 * 2;      // [1024][3072] f32
static constexpr size_t OFF_S0      = OFF_PC + 1024ull * 3072 * 4;        // [1024][1024] f32
static constexpr size_t OFF_S1      = OFF_S0 + 1024ull * 1024 * 4;
static constexpr size_t OFF_HBH0    = OFF_S1 + 1024ull * 1024 * 4;        // [64][1024] bf16
static constexpr size_t OFF_HBL0    = OFF_HBH0 + 64ull * 1024 * 2;
static constexpr size_t OFF_HBH1    = OFF_HBL0 + 64ull * 1024 * 2;
static constexpr size_t OFF_HBL1    = OFF_HBH1 + 64ull * 1024 * 2;
static constexpr size_t OFF_H320    = OFF_HBL1 + 64ull * 1024 * 2;        // [64][1024] f32
static constexpr size_t OFF_H321    = OFF_H320 + 64ull * 1024 * 4;
static constexpr size_t OFF_RHH     = OFF_H321 + 64ull * 1024 * 4;        // [64][1024] bf16
static constexpr size_t OFF_RHL     = OFF_RHH + 64ull * 1024 * 2;
static constexpr size_t OFF_BAR     = OFF_RHL + 64ull * 1024 * 2;
static constexpr size_t OFF_END     = OFF_BAR + 128;

extern "C" void kernel_launch(void* const* d_in, const int* in_sizes, int n_in,
                              void* d_out, int out_size, void* d_ws, size_t ws_size,
                              hipStream_t stream) {
  if (ws_size < OFF_END) return;  // clean fail: zeros => absmax 12.875 signature

  const float* x     = (const float*)d_in[0];
  const float* h0    = (const float*)d_in[1];
  const float* W_xz0 = (const float*)d_in[2];
  const float* W_hz0 = (const float*)d_in[3];
  const float* b_z0  = (const float*)d_in[4];
  const float* W_xr0 = (const float*)d_in[5];
  const float* W_hr0 = (const float*)d_in[6];
  const float* b_r0  = (const float*)d_in[7];
  const float* W_xg0 = (const float*)d_in[8];
  const float* W_hg0 = (const float*)d_in[9];
  const float* b_g0  = (const float*)d_in[10];
  const float* W_xz1 = (const float*)d_in[11];
  const float* W_hz1 = (const float*)d_in[12];
  const float* b_z1  = (const float*)d_in[13];
  const float* W_xr1 = (const float*)d_in[14];
  const float* W_hr1 = (const float*)d_in[15];
  const float* b_r1  = (const float*)d_in[16];
  const float* W_xg1 = (const float*)d_in[17];
  const float* W_hg1 = (const float*)d_in[18];
  const float* b_g1  = (const float*)d_in[19];
  const float* W_hy  = (const float*)d_in[20];
  const float* b_y   = (const float*)d_in[21];

  char* ws = (char*)d_ws;
  float* out_y   = (float*)d_out;                  // [64,512,512]
  float* out_hid = (float*)d_out + 16777216;       // [64,2,1024]
  unsigned* barc = (unsigned*)(ws + OFF_BAR);

  hipMemsetAsync(barc, 0, 128, stream);

  // weight transpose + hi/lo split: dst[n][k] = src[k][n]
#define TRS(W, OFF_H, OFF_L, kbits, Nsrc, total) \
  tr_cvt_split<<<2048, 256, 0, stream>>>(W, (ushort*)(ws + OFF_H), (ushort*)(ws + OFF_L), kbits, Nsrc, total)
  TRS(W_xz0, OFF_WXT0H,                  OFF_WXT0L,                   9, 1024, 1024 * 512);
  TRS(W_xr0, OFF_WXT0H + 1024ull*512*2,  OFF_WXT0L + 1024ull*512*2,   9, 1024, 1024 * 512);
  TRS(W_xg0, OFF_WXT0H + 2048ull*512*2,  OFF_WXT0L + 2048ull*512*2,   9, 1024, 1024 * 512);
  TRS(W_hz0, OFF_WHZRT0H,                OFF_WHZRT0L,                10, 1024, 1024 * 1024);
  TRS(W_hr0, OFF_WHZRT0H + 1024ull*1024*2, OFF_WHZRT0L + 1024ull*1024*2, 10, 1024, 1024 * 1024);
  TRS(W_hg0, OFF_WHGT0H,                 OFF_WHGT0L,                 10, 1024, 1024 * 1024);
  TRS(W_xz1, OFF_WXT1H,                  OFF_WXT1L,                  10, 1024, 1024 * 1024);
  TRS(W_xr1, OFF_WXT1H + 1024ull*1024*2, OFF_WXT1L + 1024ull*1024*2, 10, 1024, 1024 * 1024);
  TRS(W_xg1, OFF_WXT1H + 2048ull*1024*2, OFF_WXT1L + 2048ull*1024*2, 10, 1024, 1024 * 1024);
  TRS(W_hz1, OFF_WHZRT1H,                OFF_WHZRT1L,                10, 1024, 1024 * 1024);
  TRS(W_hr1, OFF_WHZRT1H + 1024ull*1024*2, OFF_WHZRT1L + 1024ull*1024*2, 10, 1024, 1024 * 1024);
  TRS(W_hg1, OFF_WHGT1H,                 OFF_WHGT1L,                 10, 1024, 1024 * 1024);
  TRS(W_hy,  OFF_WHYTH,                  OFF_WHYTL,                  10, 512,  512 * 1024);
#undef TRS

  float* Pc  = (float*)(ws + OFF_PC);
  float* S0c = (float*)(ws + OFF_S0);
  float* S1c = (float*)(ws + OFF_S1);

  for (int c = 0; c < 512 / TC; ++c) {
    int t0 = c * TC;
    // layer-0 input projections: Pc = x_chunk @ WxT0^T   [1024,3072], K=512
    gemm3<1, 0><<<dim3(8, 24), 256, 0, stream>>>(
        x, (const ushort*)(ws + OFF_WXT0H), (const ushort*)(ws + OFF_WXT0L),
        Pc, nullptr, 1024, 3072, 512, t0);
    // layer-0 scan
    {
      ScanArgs sa;
      sa.P = Pc; sa.bz = b_z0; sa.br = b_r0; sa.bg = b_g0;
      sa.WhzrH = (const ushort*)(ws + OFF_WHZRT0H); sa.WhzrL = (const ushort*)(ws + OFF_WHZRT0L);
      sa.WhgH = (const ushort*)(ws + OFF_WHGT0H);   sa.WhgL = (const ushort*)(ws + OFF_WHGT0L);
      sa.h0 = h0; sa.layer = 0; sa.t0 = t0;
      sa.h32g = (float*)(ws + OFF_H320);
      sa.hbh = (ushort*)(ws + OFF_HBH0); sa.hbl = (ushort*)(ws + OFF_HBL0);
      sa.rhh = (ushort*)(ws + OFF_RHH);  sa.rhl = (ushort*)(ws + OFF_RHL);
      sa.Sout = S0c; sa.hidout = out_hid;
      sa.barc = barc; sa.bar_base = (unsigned)((c * 2 + 0) * 33 * 64);
      gru_scan<<<NWG_SCAN, 256, 0, stream>>>(sa);
    }
    // layer-1 input projections: Pc = S0c @ WxT1^T  [1024,3072], K=1024
    gemm3<0, 0><<<dim3(8, 24), 256, 0, stream>>>(
        S0c, (const ushort*)(ws + OFF_WXT1H), (const ushort*)(ws + OFF_WXT1L),
        Pc, nullptr, 1024, 3072, 1024, 0);
    // layer-1 scan
    {
      ScanArgs sa;
      sa.P = Pc; sa.bz = b_z1; sa.br = b_r1; sa.bg = b_g1;
      sa.WhzrH = (const ushort*)(ws + OFF_WHZRT1H); sa.WhzrL = (const ushort*)(ws + OFF_WHZRT1L);
      sa.WhgH = (const ushort*)(ws + OFF_WHGT1H);   sa.WhgL = (const ushort*)(ws + OFF_WHGT1L);
      sa.h0 = h0; sa.layer = 1; sa.t0 = t0;
      sa.h32g = (float*)(ws + OFF_H321);
      sa.hbh = (ushort*)(ws + OFF_HBH1); sa.hbl = (ushort*)(ws + OFF_HBL1);
      sa.rhh = (ushort*)(ws + OFF_RHH);  sa.rhl = (ushort*)(ws + OFF_RHL);
      sa.Sout = S1c; sa.hidout = out_hid;
      sa.barc = barc; sa.bar_base = (unsigned)((c * 2 + 1) * 33 * 64);
      gru_scan<<<NWG_SCAN, 256, 0, stream>>>(sa);
    }
    // output projection: out_y rows = S1c @ WhyT^T + b_y  [1024,512], K=1024
    gemm3<0, 1><<<dim3(8, 4), 256, 0, stream>>>(
        S1c, (const ushort*)(ws + OFF_WHYTH), (const ushort*)(ws + OFF_WHYTL),
        out_y, b_y, 1024, 512, 1024, t0);
  }
}